// Round 2
// 420.304 us; speedup vs baseline: 1.0049x; 1.0049x over previous
//
#include <hip/hip_runtime.h>

// Problem constants (from reference) — all fp32 I/O, int32 indices.
#define BB 32
#define NN 8192
#define DIM 256
#define MM 1228
#define X_ELEMS ((size_t)BB * NN * DIM)   // 67,108,864 fp32 in masked_x
#define ROWS (BB * NN)                    // 262,144 (b, n) rows, 1 KB each
#define F4_PER_ROW (DIM / 4)              // 64 float4 per row
#define TOTAL_F4 (X_ELEMS / 4)            // 16,777,216 float4
#define NMASK (BB * MM)                   // 39,296 masked rows total

// Native clang vector: __builtin_nontemporal_* rejects HIP_vector_type (a
// class); it needs an integer/float/native-vector type. Same 16 B layout.
typedef float f32x4 __attribute__((ext_vector_type(4)));

// --- fused-flag path -------------------------------------------------------

// Zero the per-row flag array (256 KB in d_ws). uint4 stores: 16,384 threads.
__global__ __launch_bounds__(256) void aug_zero_flags(uint4* __restrict__ flags16) {
    int t = blockIdx.x * blockDim.x + threadIdx.x;   // exact grid: ROWS/16
    flags16[t] = make_uint4(0u, 0u, 0u, 0u);
}

// Mark masked rows; also emit output 1 (indices as fp32).
__global__ __launch_bounds__(256) void aug_flags(const int* __restrict__ idx,
                          unsigned char* __restrict__ flags,
                          float* __restrict__ out_idx) {
    int t = blockIdx.x * blockDim.x + threadIdx.x;
    if (t >= NMASK) return;
    int b = t / MM;                 // const divisor -> magic multiply
    int n = idx[t];                 // [0, NN)
    flags[b * NN + n] = 1;
    out_idx[t] = (float)n;
}

// One wave per row: copy x row or broadcast emb row. Branch is wave-uniform.
// x/out are pure streams (268 MB each vs 32 MB L2) -> non-temporal to avoid
// L2 allocate/evict churn between the read and write streams.
__global__ __launch_bounds__(256) void aug_main(const f32x4* __restrict__ x,
                         const f32x4* __restrict__ emb,      // 64 float4 = 1 KB
                         const unsigned char* __restrict__ flags,
                         f32x4* __restrict__ out) {
    unsigned t = blockIdx.x * blockDim.x + threadIdx.x;      // exact grid: TOTAL_F4
    unsigned row = t >> 6;
    unsigned lane = t & 63;
    if (flags[row]) {               // wave-uniform; emb is L1-resident
        out[t] = emb[lane];         // masked rows: skip the x fetch entirely
        return;
    }
    f32x4 v = __builtin_nontemporal_load(&x[t]);
    __builtin_nontemporal_store(v, &out[t]);
}

// --- fallback path (no workspace needed) -----------------------------------

__global__ __launch_bounds__(256) void aug_copy(const f32x4* __restrict__ x,
                                                f32x4* __restrict__ out) {
    unsigned t = blockIdx.x * blockDim.x + threadIdx.x;      // exact grid
    f32x4 v = __builtin_nontemporal_load(&x[t]);
    __builtin_nontemporal_store(v, &out[t]);
}

__global__ __launch_bounds__(256) void aug_scatter(const int* __restrict__ idx,
                            const f32x4* __restrict__ emb,
                            f32x4* __restrict__ out,
                            float* __restrict__ out_idx) {
    int t = blockIdx.x * blockDim.x + threadIdx.x;           // exact grid: NMASK*64
    int row = t >> 6;
    int lane = t & 63;
    int b = row / MM;
    int n = idx[row];
    size_t base = ((size_t)b * NN + (size_t)n) * F4_PER_ROW;
    out[base + lane] = emb[lane];
    if (lane == 0) out_idx[row] = (float)n;
}

extern "C" void kernel_launch(void* const* d_in, const int* in_sizes, int n_in,
                              void* d_out, int out_size, void* d_ws, size_t ws_size,
                              hipStream_t stream) {
    const f32x4* x   = (const f32x4*)d_in[0];     // fp32 [B, N, DIM]
    const int*   idx = (const int*)d_in[1];       // int32 [B, M]
    const f32x4* emb = (const f32x4*)d_in[2];     // fp32 [1, DIM]
    float* out = (float*)d_out;                   // fp32: masked_x ++ indices

    if (ws_size >= (size_t)ROWS && d_ws != nullptr) {
        unsigned char* flags = (unsigned char*)d_ws;
        aug_zero_flags<<<ROWS / 16 / 256, 256, 0, stream>>>((uint4*)flags);
        aug_flags<<<(NMASK + 255) / 256, 256, 0, stream>>>(idx, flags, out + X_ELEMS);
        aug_main<<<TOTAL_F4 / 256, 256, 0, stream>>>(x, emb, flags, (f32x4*)d_out);
    } else {
        aug_copy<<<TOTAL_F4 / 256, 256, 0, stream>>>(x, (f32x4*)d_out);
        aug_scatter<<<(NMASK * 64) / 256, 256, 0, stream>>>(
            idx, emb, (f32x4*)d_out, out + X_ELEMS);
    }
}